// Round 5
// baseline (207.640 us; speedup 1.0000x reference)
//
#include <hip/hip_runtime.h>
#include <hip/hip_bf16.h>

// Problem constants (from reference setup_inputs)
#define NB 8
#define LQ 512
#define LC 2048
#define DD 768

typedef _Float16 f16x8 __attribute__((ext_vector_type(8)));
typedef _Float16 f16x4 __attribute__((ext_vector_type(4)));
typedef float    f32x4 __attribute__((ext_vector_type(4)));

// ---------------------------------------------------------------------------
// K0a: elementwise convert ctx fp32 -> Ch fp16 [b][c][d]
// ---------------------------------------------------------------------------
__global__ __launch_bounds__(256) void convert_ctx(const float* __restrict__ src,
                                                   _Float16* __restrict__ dst) {
    const size_t i = (size_t)blockIdx.x * 256 + threadIdx.x;  // 8 elems each
    const f32x4* s = (const f32x4*)src;
    f32x4 a = s[i * 2 + 0];
    f32x4 b = s[i * 2 + 1];
    f16x8 h;
    h[0] = (_Float16)a.x; h[1] = (_Float16)a.y; h[2] = (_Float16)a.z; h[3] = (_Float16)a.w;
    h[4] = (_Float16)b.x; h[5] = (_Float16)b.y; h[6] = (_Float16)b.z; h[7] = (_Float16)b.w;
    ((f16x8*)dst)[i] = h;
}

// ---------------------------------------------------------------------------
// K0b: convert Q fp32 -> Qh [b][q][d] fp16  AND  QhT [b][d][q] fp16
// ---------------------------------------------------------------------------
__global__ __launch_bounds__(256) void preconvert_q(const float* __restrict__ Q,
                                                    _Float16* __restrict__ Qh,
                                                    _Float16* __restrict__ QhT) {
    __shared__ _Float16 lt[64][68];
    const int blk = blockIdx.x;
    const int b   = blk / 96;
    const int rem = blk % 96;
    const int q0  = (rem / 12) * 64;
    const int d0  = (rem % 12) * 64;
    const int t   = threadIdx.x;
    const int tr  = t >> 4;
    const int tc  = t & 15;

    const float* Qb  = Q  + ((size_t)b * LQ + q0) * DD + d0;
    _Float16*    Qhb = Qh + ((size_t)b * LQ + q0) * DD + d0;

#pragma unroll
    for (int i = 0; i < 4; i++) {
        const int row = i * 16 + tr;
        const int col = tc * 4;
        f32x4 v = *(const f32x4*)(Qb + (size_t)row * DD + col);
        f16x4 h;
        h.x = (_Float16)v.x; h.y = (_Float16)v.y;
        h.z = (_Float16)v.z; h.w = (_Float16)v.w;
        *(f16x4*)(Qhb + (size_t)row * DD + col) = h;
        *(f16x4*)&lt[row][col] = h;
    }
    __syncthreads();

    _Float16* QTb = QhT + ((size_t)b * DD + d0) * LQ + q0;
#pragma unroll
    for (int i = 0; i < 4; i++) {
        const int drow = i * 16 + tr;
        const int qc   = tc * 4;
        f16x4 h;
        h.x = lt[qc + 0][drow];
        h.y = lt[qc + 1][drow];
        h.z = lt[qc + 2][drow];
        h.w = lt[qc + 3][drow];
        *(f16x4*)(QTb + (size_t)drow * LQ + qc) = h;
    }
}

// ---------------------------------------------------------------------------
// Main fused kernel v5 = verified v3 structure + deep register prefetch.
// One WG = (batch, 32 ctx rows), 512 threads (8 waves), 1 block/CU
// (__launch_bounds__(512,2) -> 256-VGPR cap so the prefetch pipeline SURVIVES;
//  R3's (512,4) collapsed it to VGPR=64 and serialized every load).
// Phase A: A-tile (32x768 fp16) in LDS; B (Qh) depth-4 register rotation
//   (bb[4][4] = 64 VGPRs = 4KB/wave in flight; 8 waves/CU -> 32KB/CU in
//   flight >= 200cyc x 56B/cyc L2 latency-BW product -> L2-BW-bound).
// Phase B: softmax over q; P -> ldsP [32][520] (aliases ldsA).
// Phase C: awq = P @ Q; B (QhT) depth-3 rotation (cb[3][6] = 72 VGPRs).
// Epilogue: out = Ch * awq.
// ---------------------------------------------------------------------------
#define LDSA_STRIDE 776   // 768+8 halves: 16B-aligned rows, 2-way banks (free)
#define PSTRIDE     520   // 512+8 halves

template <bool USE_CH>
__global__ __launch_bounds__(512, 2) void gated_attn(const float* __restrict__ ctx,
                                                     const _Float16* __restrict__ Ch,
                                                     const _Float16* __restrict__ Qh,
                                                     const _Float16* __restrict__ QhT,
                                                     float* __restrict__ out) {
    __shared__ __align__(16) char smem[32 * LDSA_STRIDE * 2 + 2 * 8 * 32 * 4];
    _Float16* ldsA = (_Float16*)smem;                  // phase A: staged Ch tile
    _Float16* ldsP = (_Float16*)smem;                  // phase B/C: P (aliases)
    float (*red_max)[32] = (float (*)[32])(smem + 32 * LDSA_STRIDE * 2);
    float (*red_sum)[32] = red_max + 8;

    const int b    = blockIdx.x & 7;          // XCD-affine batch
    const int c0   = (blockIdx.x >> 3) * 32;  // context tile
    const int t    = threadIdx.x;
    const int w    = t >> 6;                  // wave 0..7
    const int lane = t & 63;
    const int quad = lane >> 4;
    const int l15  = lane & 15;

    const float*    Cb  = ctx + ((size_t)b * LC + c0) * DD;
    const _Float16* Chb = USE_CH ? (Ch + ((size_t)b * LC + c0) * DD) : nullptr;
    const _Float16* Qhb = Qh + (size_t)b * LQ * DD;

    // ---------------- Stage A-tile into LDS (32 rows x 768 halves) ----------
#pragma unroll
    for (int i = 0; i < 6; i++) {
        const int idx  = i * 512 + t;
        const int row  = idx / 96;
        const int colc = idx % 96;        // 8-half chunk index
        f16x8 v;
        if (USE_CH) {
            v = *(const f16x8*)(Chb + (size_t)row * DD + colc * 8);
        } else {
            const float* p = Cb + (size_t)row * DD + colc * 8;
            f32x4 f0 = *(const f32x4*)p;
            f32x4 f1 = *(const f32x4*)(p + 4);
            v[0] = (_Float16)f0.x; v[1] = (_Float16)f0.y;
            v[2] = (_Float16)f0.z; v[3] = (_Float16)f0.w;
            v[4] = (_Float16)f1.x; v[5] = (_Float16)f1.y;
            v[6] = (_Float16)f1.z; v[7] = (_Float16)f1.w;
        }
        *(f16x8*)&ldsA[row * LDSA_STRIDE + colc * 8] = v;
    }
    __syncthreads();

    // ---------------- Phase A: S = A_tile @ Qh^T ----------------
    f32x4 acc[2][4];
#pragma unroll
    for (int mt = 0; mt < 2; mt++)
#pragma unroll
        for (int nt = 0; nt < 4; nt++)
            acc[mt][nt] = (f32x4){0.f, 0.f, 0.f, 0.f};

    // depth-4 rotating register buffers for B (Qh) fragments
    f16x8 bb[4][4];
#pragma unroll
    for (int p = 0; p < 4; p++)
#pragma unroll
        for (int nt = 0; nt < 4; nt++)
            bb[p][nt] = *(const f16x8*)(Qhb + (size_t)(w * 64 + nt * 16 + l15) * DD + p * 32 + quad * 8);

#pragma unroll
    for (int kc = 0; kc < 24; kc++) {
        const int k0 = kc * 32;
        f16x8 a0 = *(const f16x8*)&ldsA[(size_t)l15        * LDSA_STRIDE + k0 + quad * 8];
        f16x8 a1 = *(const f16x8*)&ldsA[(size_t)(16 + l15) * LDSA_STRIDE + k0 + quad * 8];
#pragma unroll
        for (int nt = 0; nt < 4; nt++) {
            acc[0][nt] = __builtin_amdgcn_mfma_f32_16x16x32_f16(a0, bb[kc & 3][nt], acc[0][nt], 0, 0, 0);
            acc[1][nt] = __builtin_amdgcn_mfma_f32_16x16x32_f16(a1, bb[kc & 3][nt], acc[1][nt], 0, 0, 0);
        }
        if (kc + 4 < 24) {
#pragma unroll
            for (int nt = 0; nt < 4; nt++)
                bb[kc & 3][nt] = *(const f16x8*)(Qhb + (size_t)(w * 64 + nt * 16 + l15) * DD + (k0 + 128) + quad * 8);
        }
    }

    // ---------------- Phase B: softmax over q ----------------
    float rm[2][4];
#pragma unroll
    for (int mt = 0; mt < 2; mt++)
#pragma unroll
        for (int r = 0; r < 4; r++)
            rm[mt][r] = -1e30f;
#pragma unroll
    for (int mt = 0; mt < 2; mt++)
#pragma unroll
        for (int nt = 0; nt < 4; nt++) {
            rm[mt][0] = fmaxf(rm[mt][0], acc[mt][nt].x);
            rm[mt][1] = fmaxf(rm[mt][1], acc[mt][nt].y);
            rm[mt][2] = fmaxf(rm[mt][2], acc[mt][nt].z);
            rm[mt][3] = fmaxf(rm[mt][3], acc[mt][nt].w);
        }
#pragma unroll
    for (int off = 1; off < 16; off <<= 1)
#pragma unroll
        for (int mt = 0; mt < 2; mt++)
#pragma unroll
            for (int r = 0; r < 4; r++)
                rm[mt][r] = fmaxf(rm[mt][r], __shfl_xor(rm[mt][r], off));
    if (l15 == 0) {
#pragma unroll
        for (int mt = 0; mt < 2; mt++)
#pragma unroll
            for (int r = 0; r < 4; r++)
                red_max[w][mt * 16 + quad * 4 + r] = rm[mt][r];
    }
    __syncthreads();
    float fm[2][4];
#pragma unroll
    for (int mt = 0; mt < 2; mt++)
#pragma unroll
        for (int r = 0; r < 4; r++) {
            const int row = mt * 16 + quad * 4 + r;
            float m0 = fmaxf(fmaxf(red_max[0][row], red_max[1][row]),
                             fmaxf(red_max[2][row], red_max[3][row]));
            float m1 = fmaxf(fmaxf(red_max[4][row], red_max[5][row]),
                             fmaxf(red_max[6][row], red_max[7][row]));
            fm[mt][r] = fmaxf(m0, m1);
        }
    float rs[2][4];
#pragma unroll
    for (int mt = 0; mt < 2; mt++)
#pragma unroll
        for (int r = 0; r < 4; r++)
            rs[mt][r] = 0.f;
#pragma unroll
    for (int mt = 0; mt < 2; mt++)
#pragma unroll
        for (int nt = 0; nt < 4; nt++) {
            float e0 = __expf(acc[mt][nt].x - fm[mt][0]);
            float e1 = __expf(acc[mt][nt].y - fm[mt][1]);
            float e2 = __expf(acc[mt][nt].z - fm[mt][2]);
            float e3 = __expf(acc[mt][nt].w - fm[mt][3]);
            acc[mt][nt].x = e0; acc[mt][nt].y = e1;
            acc[mt][nt].z = e2; acc[mt][nt].w = e3;
            rs[mt][0] += e0; rs[mt][1] += e1; rs[mt][2] += e2; rs[mt][3] += e3;
        }
#pragma unroll
    for (int off = 1; off < 16; off <<= 1)
#pragma unroll
        for (int mt = 0; mt < 2; mt++)
#pragma unroll
            for (int r = 0; r < 4; r++)
                rs[mt][r] += __shfl_xor(rs[mt][r], off);
    if (l15 == 0) {
#pragma unroll
        for (int mt = 0; mt < 2; mt++)
#pragma unroll
            for (int r = 0; r < 4; r++)
                red_sum[w][mt * 16 + quad * 4 + r] = rs[mt][r];
    }
    __syncthreads();
#pragma unroll
    for (int mt = 0; mt < 2; mt++)
#pragma unroll
        for (int r = 0; r < 4; r++) {
            const int row = mt * 16 + quad * 4 + r;
            float s = 0.f;
#pragma unroll
            for (int j = 0; j < 8; j++) s += red_sum[j][row];
            const float inv = 1.0f / s;
#pragma unroll
            for (int nt = 0; nt < 4; nt++) {
                const int q = w * 64 + nt * 16 + l15;
                float v = (r == 0 ? acc[mt][nt].x : r == 1 ? acc[mt][nt].y
                          : r == 2 ? acc[mt][nt].z : acc[mt][nt].w);
                ldsP[row * PSTRIDE + q] = (_Float16)(v * inv);
            }
        }
    __syncthreads();

    // ---------------- Phase C: awq = P @ Q ----------------
    f32x4 acc2[2][6];
#pragma unroll
    for (int mt = 0; mt < 2; mt++)
#pragma unroll
        for (int nt = 0; nt < 6; nt++)
            acc2[mt][nt] = (f32x4){0.f, 0.f, 0.f, 0.f};

    const _Float16* QTb = QhT + (size_t)b * DD * LQ;
    // depth-3 rotating register buffers for B (QhT) fragments
    f16x8 cb[3][6];
#pragma unroll
    for (int p = 0; p < 3; p++)
#pragma unroll
        for (int nt = 0; nt < 6; nt++)
            cb[p][nt] = *(const f16x8*)(QTb + (size_t)(w * 96 + nt * 16 + l15) * LQ + p * 32 + quad * 8);

#pragma unroll
    for (int kc = 0; kc < 16; kc++) {
        const int k0 = kc * 32;
        f16x8 a0 = *(const f16x8*)&ldsP[(size_t)l15        * PSTRIDE + k0 + quad * 8];
        f16x8 a1 = *(const f16x8*)&ldsP[(size_t)(16 + l15) * PSTRIDE + k0 + quad * 8];
#pragma unroll
        for (int nt = 0; nt < 6; nt++) {
            acc2[0][nt] = __builtin_amdgcn_mfma_f32_16x16x32_f16(a0, cb[kc % 3][nt], acc2[0][nt], 0, 0, 0);
            acc2[1][nt] = __builtin_amdgcn_mfma_f32_16x16x32_f16(a1, cb[kc % 3][nt], acc2[1][nt], 0, 0, 0);
        }
        if (kc + 3 < 16) {
#pragma unroll
            for (int nt = 0; nt < 6; nt++)
                cb[kc % 3][nt] = *(const f16x8*)(QTb + (size_t)(w * 96 + nt * 16 + l15) * LQ + (k0 + 96) + quad * 8);
        }
    }

    // ---------------- Epilogue: out = gate * awq ----------------
#pragma unroll
    for (int mt = 0; mt < 2; mt++)
#pragma unroll
        for (int nt = 0; nt < 6; nt++) {
            const int col = w * 96 + nt * 16 + l15;
#pragma unroll
            for (int r = 0; r < 4; r++) {
                const int rl  = mt * 16 + quad * 4 + r;
                const int row = c0 + rl;
                const size_t idx = ((size_t)b * LC + row) * DD + col;
                float v = (r == 0 ? acc2[mt][nt].x : r == 1 ? acc2[mt][nt].y
                          : r == 2 ? acc2[mt][nt].z : acc2[mt][nt].w);
                float g = USE_CH ? (float)Chb[(size_t)rl * DD + col] : ctx[idx];
                out[idx] = g * v;
            }
        }
}

extern "C" void kernel_launch(void* const* d_in, const int* in_sizes, int n_in,
                              void* d_out, int out_size, void* d_ws, size_t ws_size,
                              hipStream_t stream) {
    const float* ctx = (const float*)d_in[0];   // [8][2048][768] f32
    const float* q   = (const float*)d_in[1];   // [8][512][768]  f32
    float* out = (float*)d_out;

    const size_t nQ = (size_t)NB * LQ * DD;     // 3,145,728
    const size_t nC = (size_t)NB * LC * DD;     // 12,582,912
    _Float16* Qh  = (_Float16*)d_ws;
    _Float16* QhT = Qh + nQ;
    _Float16* Ch  = QhT + nQ;
    const bool use_ch = ws_size >= (2 * nQ + nC) * sizeof(_Float16);

    preconvert_q<<<dim3(NB * 96), dim3(256), 0, stream>>>(q, Qh, QhT);
    if (use_ch) {
        convert_ctx<<<dim3((int)(nC / (256 * 8))), dim3(256), 0, stream>>>(ctx, Ch);
        gated_attn<true><<<dim3(NB * (LC / 32)), dim3(512), 0, stream>>>(ctx, Ch, Qh, QhT, out);
    } else {
        gated_attn<false><<<dim3(NB * (LC / 32)), dim3(512), 0, stream>>>(ctx, nullptr, Qh, QhT, out);
    }
}

// Round 6
// 180.670 us; speedup vs baseline: 1.1493x; 1.1493x over previous
//
#include <hip/hip_runtime.h>
#include <hip/hip_bf16.h>

// Problem constants (from reference setup_inputs)
#define NB 8
#define LQ 512
#define LC 2048
#define DD 768

typedef _Float16 f16x8 __attribute__((ext_vector_type(8)));
typedef _Float16 f16x4 __attribute__((ext_vector_type(4)));
typedef float    f32x4 __attribute__((ext_vector_type(4)));

// ---------------------------------------------------------------------------
// K0a: elementwise convert ctx fp32 -> Ch fp16 [b][c][d]
// ---------------------------------------------------------------------------
__global__ __launch_bounds__(256) void convert_ctx(const float* __restrict__ src,
                                                   _Float16* __restrict__ dst) {
    const size_t i = (size_t)blockIdx.x * 256 + threadIdx.x;  // 8 elems each
    const f32x4* s = (const f32x4*)src;
    f32x4 a = s[i * 2 + 0];
    f32x4 b = s[i * 2 + 1];
    f16x8 h;
    h[0] = (_Float16)a.x; h[1] = (_Float16)a.y; h[2] = (_Float16)a.z; h[3] = (_Float16)a.w;
    h[4] = (_Float16)b.x; h[5] = (_Float16)b.y; h[6] = (_Float16)b.z; h[7] = (_Float16)b.w;
    ((f16x8*)dst)[i] = h;
}

// ---------------------------------------------------------------------------
// K0b: convert Q fp32 -> Qh [b][q][d] fp16  AND  QhT [b][d][q] fp16
// ---------------------------------------------------------------------------
__global__ __launch_bounds__(256) void preconvert_q(const float* __restrict__ Q,
                                                    _Float16* __restrict__ Qh,
                                                    _Float16* __restrict__ QhT) {
    __shared__ _Float16 lt[64][68];
    const int blk = blockIdx.x;
    const int b   = blk / 96;
    const int rem = blk % 96;
    const int q0  = (rem / 12) * 64;
    const int d0  = (rem % 12) * 64;
    const int t   = threadIdx.x;
    const int tr  = t >> 4;
    const int tc  = t & 15;

    const float* Qb  = Q  + ((size_t)b * LQ + q0) * DD + d0;
    _Float16*    Qhb = Qh + ((size_t)b * LQ + q0) * DD + d0;

#pragma unroll
    for (int i = 0; i < 4; i++) {
        const int row = i * 16 + tr;
        const int col = tc * 4;
        f32x4 v = *(const f32x4*)(Qb + (size_t)row * DD + col);
        f16x4 h;
        h.x = (_Float16)v.x; h.y = (_Float16)v.y;
        h.z = (_Float16)v.z; h.w = (_Float16)v.w;
        *(f16x4*)(Qhb + (size_t)row * DD + col) = h;
        *(f16x4*)&lt[row][col] = h;
    }
    __syncthreads();

    _Float16* QTb = QhT + ((size_t)b * DD + d0) * LQ + q0;
#pragma unroll
    for (int i = 0; i < 4; i++) {
        const int drow = i * 16 + tr;
        const int qc   = tc * 4;
        f16x4 h;
        h.x = lt[qc + 0][drow];
        h.y = lt[qc + 1][drow];
        h.z = lt[qc + 2][drow];
        h.w = lt[qc + 3][drow];
        *(f16x4*)(QTb + (size_t)drow * LQ + qc) = h;
    }
}

// ---------------------------------------------------------------------------
// Main fused kernel v6: m93-style cooperative LDS staging, double-buffered,
// ONE barrier per K-chunk. The compiler cannot collapse this pipeline (the
// ds_write is a real consumer of the global load; its vmcnt-wait lands AFTER
// the MFMA block, so L2 latency hides behind compute) — unlike the register
// rotations of R3/R5 which the scheduler sank (VGPR_Count 64/68).
// One WG = (batch, 32 ctx rows), 512 threads (8 waves), 1 block/CU.
// Phase A: A-tile 32x768 fp16 in ldsA; B = Qh streamed in 24 chunks
//   [512q x 32k] = 32KB, dbuf Bbuf0/1. Per thread 4x16B load + 4 ds_write.
// Phase B: softmax over q; P -> ldsP [32][520]. C-chunk0 global loads issued
//   right after phase A; ds_written mid-softmax (overlap).
// Phase C: B = QhT streamed in 16 chunks [768d x 32q] = 48KB, dbuf Cbuf0/1
//   (aliases dead ldsA/Bbuf). Epilogue: out = Ch * awq.
// LDS map (bytes): ldsA [0,49664) | ldsP [0,33280) | Bbuf0 [49664,82432)
//   Bbuf1 [82432,115200) | Cbuf0 [33280,82432) Cbuf1 [82432,131584)
//   (phase-ordered aliasing; all prior readers drained at the softmax
//   barriers) | red [131584,133632).  Total 133632.
// ---------------------------------------------------------------------------
#define LDSA_STRIDE 776
#define PSTRIDE     520
#define BBUF0_OFF   49664
#define CBUF0_OFF   33280
#define CBUF1_OFF   82432
#define RED_OFF     131584
#define SMEM_BYTES  133632

template <bool USE_CH>
__global__ __launch_bounds__(512, 2) void gated_attn(const float* __restrict__ ctx,
                                                     const _Float16* __restrict__ Ch,
                                                     const _Float16* __restrict__ Qh,
                                                     const _Float16* __restrict__ QhT,
                                                     float* __restrict__ out) {
    __shared__ __align__(16) char smem[SMEM_BYTES];
    _Float16* ldsA = (_Float16*)smem;
    _Float16* ldsP = (_Float16*)smem;
    float (*red_max)[32] = (float (*)[32])(smem + RED_OFF);
    float (*red_sum)[32] = (float (*)[32])(smem + RED_OFF + 1024);

    const int b    = blockIdx.x & 7;          // XCD-affine batch
    const int c0   = (blockIdx.x >> 3) * 32;
    const int t    = threadIdx.x;
    const int w    = t >> 6;                  // wave 0..7
    const int lane = t & 63;
    const int quad = lane >> 4;
    const int l15  = lane & 15;
    const int srow = t >> 2;                  // staging row 0..127
    const int ssub = t & 3;                   // staging 16B piece 0..3

    const float*    Cb  = ctx + ((size_t)b * LC + c0) * DD;
    const _Float16* Chb = USE_CH ? (Ch + ((size_t)b * LC + c0) * DD) : nullptr;
    const _Float16* Qhb = Qh  + (size_t)b * LQ * DD;
    const _Float16* QTb = QhT + (size_t)b * DD * LQ;

    // ---------------- Stage A-tile into ldsA ----------------
#pragma unroll
    for (int i = 0; i < 6; i++) {
        const int idx  = i * 512 + t;
        const int row  = idx / 96;
        const int colc = idx % 96;
        f16x8 v;
        if (USE_CH) {
            v = *(const f16x8*)(Chb + (size_t)row * DD + colc * 8);
        } else {
            const float* p = Cb + (size_t)row * DD + colc * 8;
            f32x4 f0 = *(const f32x4*)p;
            f32x4 f1 = *(const f32x4*)(p + 4);
            v[0] = (_Float16)f0.x; v[1] = (_Float16)f0.y;
            v[2] = (_Float16)f0.z; v[3] = (_Float16)f0.w;
            v[4] = (_Float16)f1.x; v[5] = (_Float16)f1.y;
            v[6] = (_Float16)f1.z; v[7] = (_Float16)f1.w;
        }
        *(f16x8*)&ldsA[row * LDSA_STRIDE + colc * 8] = v;
    }

    // ---------------- Stage B chunk 0 -> Bbuf0 ----------------
    f16x8 sb[4];
#pragma unroll
    for (int j = 0; j < 4; j++)
        sb[j] = *(const f16x8*)(Qhb + (size_t)(j * 128 + srow) * DD + ssub * 8);
    {
        _Float16* bw = (_Float16*)(smem + BBUF0_OFF);
#pragma unroll
        for (int j = 0; j < 4; j++)
            *(f16x8*)&bw[(j * 128 + srow) * 32 + ssub * 8] = sb[j];
    }
    __syncthreads();   // publishes ldsA + Bbuf0

    // ---------------- Phase A: S = A @ Qh^T, 1 barrier/chunk ----------------
    f32x4 acc[2][4];
#pragma unroll
    for (int mt = 0; mt < 2; mt++)
#pragma unroll
        for (int nt = 0; nt < 4; nt++)
            acc[mt][nt] = (f32x4){0.f, 0.f, 0.f, 0.f};

#pragma unroll
    for (int kc = 0; kc < 24; kc++) {
        // issue next chunk's global loads early (consumed by ds_write below)
        if (kc + 1 < 24) {
#pragma unroll
            for (int j = 0; j < 4; j++)
                sb[j] = *(const f16x8*)(Qhb + (size_t)(j * 128 + srow) * DD + (kc + 1) * 32 + ssub * 8);
        }
        if (kc > 0) __syncthreads();  // publish Bbuf[kc&1]; drain readers of Bbuf[(kc+1)&1]
        const _Float16* bbuf = (const _Float16*)(smem + BBUF0_OFF + (kc & 1) * 32768);
        f16x8 a0 = *(const f16x8*)&ldsA[(size_t)l15        * LDSA_STRIDE + kc * 32 + quad * 8];
        f16x8 a1 = *(const f16x8*)&ldsA[(size_t)(16 + l15) * LDSA_STRIDE + kc * 32 + quad * 8];
#pragma unroll
        for (int nt = 0; nt < 4; nt++) {
            f16x8 bq = *(const f16x8*)&bbuf[(w * 64 + nt * 16 + l15) * 32 + quad * 8];
            acc[0][nt] = __builtin_amdgcn_mfma_f32_16x16x32_f16(a0, bq, acc[0][nt], 0, 0, 0);
            acc[1][nt] = __builtin_amdgcn_mfma_f32_16x16x32_f16(a1, bq, acc[1][nt], 0, 0, 0);
        }
        if (kc + 1 < 24) {
            _Float16* bw = (_Float16*)(smem + BBUF0_OFF + ((kc + 1) & 1) * 32768);
#pragma unroll
            for (int j = 0; j < 4; j++)
                *(f16x8*)&bw[(j * 128 + srow) * 32 + ssub * 8] = sb[j];   // vmcnt wait lands here
        }
    }

    // issue phase-C chunk-0 global loads now (overlap with softmax)
    f16x8 sc[6];
#pragma unroll
    for (int j = 0; j < 6; j++)
        sc[j] = *(const f16x8*)(QTb + (size_t)(j * 128 + srow) * LQ + ssub * 8);

    // ---------------- Phase B: softmax over q ----------------
    float rm[2][4];
#pragma unroll
    for (int mt = 0; mt < 2; mt++)
#pragma unroll
        for (int r = 0; r < 4; r++)
            rm[mt][r] = -1e30f;
#pragma unroll
    for (int mt = 0; mt < 2; mt++)
#pragma unroll
        for (int nt = 0; nt < 4; nt++) {
            rm[mt][0] = fmaxf(rm[mt][0], acc[mt][nt].x);
            rm[mt][1] = fmaxf(rm[mt][1], acc[mt][nt].y);
            rm[mt][2] = fmaxf(rm[mt][2], acc[mt][nt].z);
            rm[mt][3] = fmaxf(rm[mt][3], acc[mt][nt].w);
        }
#pragma unroll
    for (int off = 1; off < 16; off <<= 1)
#pragma unroll
        for (int mt = 0; mt < 2; mt++)
#pragma unroll
            for (int r = 0; r < 4; r++)
                rm[mt][r] = fmaxf(rm[mt][r], __shfl_xor(rm[mt][r], off));
    if (l15 == 0) {
#pragma unroll
        for (int mt = 0; mt < 2; mt++)
#pragma unroll
            for (int r = 0; r < 4; r++)
                red_max[w][mt * 16 + quad * 4 + r] = rm[mt][r];
    }
    __syncthreads();   // [X1] publish red_max; ALL phase-A LDS reads drained

    // ds_write C-chunk0 -> Cbuf0 (aliases dead ldsA-tail/Bbuf0 — safe after X1)
    {
        _Float16* cw = (_Float16*)(smem + CBUF0_OFF);
#pragma unroll
        for (int j = 0; j < 6; j++)
            *(f16x8*)&cw[(j * 128 + srow) * 32 + ssub * 8] = sc[j];
    }

    float fm[2][4];
#pragma unroll
    for (int mt = 0; mt < 2; mt++)
#pragma unroll
        for (int r = 0; r < 4; r++) {
            const int row = mt * 16 + quad * 4 + r;
            float m0 = fmaxf(fmaxf(red_max[0][row], red_max[1][row]),
                             fmaxf(red_max[2][row], red_max[3][row]));
            float m1 = fmaxf(fmaxf(red_max[4][row], red_max[5][row]),
                             fmaxf(red_max[6][row], red_max[7][row]));
            fm[mt][r] = fmaxf(m0, m1);
        }
    float rs[2][4];
#pragma unroll
    for (int mt = 0; mt < 2; mt++)
#pragma unroll
        for (int r = 0; r < 4; r++)
            rs[mt][r] = 0.f;
#pragma unroll
    for (int mt = 0; mt < 2; mt++)
#pragma unroll
        for (int nt = 0; nt < 4; nt++) {
            float e0 = __expf(acc[mt][nt].x - fm[mt][0]);
            float e1 = __expf(acc[mt][nt].y - fm[mt][1]);
            float e2 = __expf(acc[mt][nt].z - fm[mt][2]);
            float e3 = __expf(acc[mt][nt].w - fm[mt][3]);
            acc[mt][nt].x = e0; acc[mt][nt].y = e1;
            acc[mt][nt].z = e2; acc[mt][nt].w = e3;
            rs[mt][0] += e0; rs[mt][1] += e1; rs[mt][2] += e2; rs[mt][3] += e3;
        }
#pragma unroll
    for (int off = 1; off < 16; off <<= 1)
#pragma unroll
        for (int mt = 0; mt < 2; mt++)
#pragma unroll
            for (int r = 0; r < 4; r++)
                rs[mt][r] += __shfl_xor(rs[mt][r], off);
    if (l15 == 0) {
#pragma unroll
        for (int mt = 0; mt < 2; mt++)
#pragma unroll
            for (int r = 0; r < 4; r++)
                red_sum[w][mt * 16 + quad * 4 + r] = rs[mt][r];
    }
    __syncthreads();   // [X2] publish red_sum + Cbuf0
#pragma unroll
    for (int mt = 0; mt < 2; mt++)
#pragma unroll
        for (int r = 0; r < 4; r++) {
            const int row = mt * 16 + quad * 4 + r;
            float s = 0.f;
#pragma unroll
            for (int j = 0; j < 8; j++) s += red_sum[j][row];
            const float inv = 1.0f / s;
#pragma unroll
            for (int nt = 0; nt < 4; nt++) {
                const int q = w * 64 + nt * 16 + l15;
                float v = (r == 0 ? acc[mt][nt].x : r == 1 ? acc[mt][nt].y
                          : r == 2 ? acc[mt][nt].z : acc[mt][nt].w);
                ldsP[row * PSTRIDE + q] = (_Float16)(v * inv);
            }
        }
    __syncthreads();   // [X3] publish ldsP (serves as phase-C kc=0 barrier)

    // ---------------- Phase C: awq = P @ Q, 1 barrier/chunk ----------------
    f32x4 acc2[2][6];
#pragma unroll
    for (int mt = 0; mt < 2; mt++)
#pragma unroll
        for (int nt = 0; nt < 6; nt++)
            acc2[mt][nt] = (f32x4){0.f, 0.f, 0.f, 0.f};

#pragma unroll
    for (int kc = 0; kc < 16; kc++) {
        if (kc + 1 < 16) {
#pragma unroll
            for (int j = 0; j < 6; j++)
                sc[j] = *(const f16x8*)(QTb + (size_t)(j * 128 + srow) * LQ + (kc + 1) * 32 + ssub * 8);
        }
        if (kc > 0) __syncthreads();
        const _Float16* cbuf = (const _Float16*)(smem + ((kc & 1) ? CBUF1_OFF : CBUF0_OFF));
        f16x8 a0 = *(const f16x8*)&ldsP[(size_t)l15        * PSTRIDE + kc * 32 + quad * 8];
        f16x8 a1 = *(const f16x8*)&ldsP[(size_t)(16 + l15) * PSTRIDE + kc * 32 + quad * 8];
#pragma unroll
        for (int nt = 0; nt < 6; nt++) {
            f16x8 cq = *(const f16x8*)&cbuf[(w * 96 + nt * 16 + l15) * 32 + quad * 8];
            acc2[0][nt] = __builtin_amdgcn_mfma_f32_16x16x32_f16(a0, cq, acc2[0][nt], 0, 0, 0);
            acc2[1][nt] = __builtin_amdgcn_mfma_f32_16x16x32_f16(a1, cq, acc2[1][nt], 0, 0, 0);
        }
        if (kc + 1 < 16) {
            _Float16* cw = (_Float16*)(smem + (((kc + 1) & 1) ? CBUF1_OFF : CBUF0_OFF));
#pragma unroll
            for (int j = 0; j < 6; j++)
                *(f16x8*)&cw[(j * 128 + srow) * 32 + ssub * 8] = sc[j];
        }
    }

    // ---------------- Epilogue: out = gate * awq ----------------
#pragma unroll
    for (int mt = 0; mt < 2; mt++)
#pragma unroll
        for (int nt = 0; nt < 6; nt++) {
            const int col = w * 96 + nt * 16 + l15;
#pragma unroll
            for (int r = 0; r < 4; r++) {
                const int rl  = mt * 16 + quad * 4 + r;
                const int row = c0 + rl;
                const size_t idx = ((size_t)b * LC + row) * DD + col;
                float v = (r == 0 ? acc2[mt][nt].x : r == 1 ? acc2[mt][nt].y
                          : r == 2 ? acc2[mt][nt].z : acc2[mt][nt].w);
                float g = USE_CH ? (float)Chb[(size_t)rl * DD + col] : ctx[idx];
                out[idx] = g * v;
            }
        }
}

extern "C" void kernel_launch(void* const* d_in, const int* in_sizes, int n_in,
                              void* d_out, int out_size, void* d_ws, size_t ws_size,
                              hipStream_t stream) {
    const float* ctx = (const float*)d_in[0];   // [8][2048][768] f32
    const float* q   = (const float*)d_in[1];   // [8][512][768]  f32
    float* out = (float*)d_out;

    const size_t nQ = (size_t)NB * LQ * DD;     // 3,145,728
    const size_t nC = (size_t)NB * LC * DD;     // 12,582,912
    _Float16* Qh  = (_Float16*)d_ws;
    _Float16* QhT = Qh + nQ;
    _Float16* Ch  = QhT + nQ;
    const bool use_ch = ws_size >= (2 * nQ + nC) * sizeof(_Float16);

    preconvert_q<<<dim3(NB * 96), dim3(256), 0, stream>>>(q, Qh, QhT);
    if (use_ch) {
        convert_ctx<<<dim3((int)(nC / (256 * 8))), dim3(256), 0, stream>>>(ctx, Ch);
        gated_attn<true><<<dim3(NB * (LC / 32)), dim3(512), 0, stream>>>(ctx, Ch, Qh, QhT, out);
    } else {
        gated_attn<false><<<dim3(NB * (LC / 32)), dim3(512), 0, stream>>>(ctx, nullptr, Qh, QhT, out);
    }
}